// Round 8
// baseline (315.424 us; speedup 1.0000x reference)
//
#include <hip/hip_runtime.h>
#include <hip/hip_bf16.h>

#define B_SZ 4096
#define NHID_ 2048

typedef __bf16 bf16x8 __attribute__((ext_vector_type(8)));
typedef float f32x4 __attribute__((ext_vector_type(4)));

__device__ __forceinline__ float sigmoidf_(float x) { return 1.f / (1.f + expf(-x)); }
__device__ __forceinline__ float b2f_(unsigned short u) {
    unsigned v = (unsigned)u << 16;
    return __builtin_bit_cast(float, v);
}

#define GLDS16(gp, lp) __builtin_amdgcn_global_load_lds( \
    (const __attribute__((address_space(1))) void*)(gp), \
    (__attribute__((address_space(3))) void*)(lp), 16, 0, 0)

// ---------------------------------------------------------------------------
// fp32 -> bf16 conversion, 4 elems/thread, grid-stride
// ---------------------------------------------------------------------------
__global__ __launch_bounds__(256) void f2b_kernel(
    const float* __restrict__ src, __hip_bfloat16* __restrict__ dst, long n4)
{
    long i = (long)blockIdx.x * 256 + threadIdx.x;
    const long stride = (long)gridDim.x * 256;
    for (; i < n4; i += stride) {
        float4 v = ((const float4*)src)[i];
        __hip_bfloat16 b0 = __float2bfloat16(v.x);
        __hip_bfloat16 b1 = __float2bfloat16(v.y);
        __hip_bfloat16 b2 = __float2bfloat16(v.z);
        __hip_bfloat16 b3 = __float2bfloat16(v.w);
        ushort4 u;
        u.x = *(unsigned short*)&b0; u.y = *(unsigned short*)&b1;
        u.z = *(unsigned short*)&b2; u.w = *(unsigned short*)&b3;
        ((ushort4*)dst)[i] = u;
    }
}

// ---------------------------------------------------------------------------
// Wih convert + cb: Wihb = bf16(Wih); cb[j] = dot(fc_i_b, Wih[j,:]) + bih[j]
// ---------------------------------------------------------------------------
__global__ __launch_bounds__(256) void wih_prep(
    const float* __restrict__ Wih, const float* __restrict__ fc_i_b,
    const float* __restrict__ bih, __hip_bfloat16* __restrict__ Wihb,
    float* __restrict__ cb)
{
    long j = blockIdx.x;
    const float* row = Wih + j * 1024;
    __hip_bfloat16* drow = Wihb + j * 1024;
    int i = threadIdx.x * 4;
    float4 v = *(const float4*)(row + i);
    __hip_bfloat16 b0 = __float2bfloat16(v.x);
    __hip_bfloat16 b1 = __float2bfloat16(v.y);
    __hip_bfloat16 b2 = __float2bfloat16(v.z);
    __hip_bfloat16 b3 = __float2bfloat16(v.w);
    ushort4 u;
    u.x = *(unsigned short*)&b0; u.y = *(unsigned short*)&b1;
    u.z = *(unsigned short*)&b2; u.w = *(unsigned short*)&b3;
    *(ushort4*)(drow + i) = u;
    float s = fc_i_b[i] * v.x + fc_i_b[i + 1] * v.y +
              fc_i_b[i + 2] * v.z + fc_i_b[i + 3] * v.w;
#pragma unroll
    for (int off = 32; off > 0; off >>= 1) s += __shfl_xor(s, off, 64);
    __shared__ float red[4];
    if ((threadIdx.x & 63) == 0) red[threadIdx.x >> 6] = s;
    __syncthreads();
    if (threadIdx.x == 0) cb[j] = red[0] + red[1] + red[2] + red[3] + bih[j];
}

// ---------------------------------------------------------------------------
// Transpose + convert: dst[c*ldd + r] (bf16) = src[r*C + c] (f32), batched z.
// ---------------------------------------------------------------------------
__global__ __launch_bounds__(256) void tconv_kernel(
    const float* __restrict__ src, int C, long sS,
    __hip_bfloat16* __restrict__ dst, int ldd, long sD)
{
    src += (long)blockIdx.z * sS;
    dst += (long)blockIdx.z * sD;
    const int r0 = blockIdx.y * 32, c0 = blockIdx.x * 32;
    const int tx = threadIdx.x & 31, ty = threadIdx.x >> 5;
    __shared__ float tile[32][33];
#pragma unroll
    for (int i = 0; i < 4; ++i)
        tile[ty + i * 8][tx] = src[(long)(r0 + ty + i * 8) * C + c0 + tx];
    __syncthreads();
#pragma unroll
    for (int i = 0; i < 4; ++i)
        dst[(long)(c0 + ty + i * 8) * ldd + r0 + tx] = __float2bfloat16(tile[tx][ty + i * 8]);
}

// ---------------------------------------------------------------------------
// Build fcgT (512 x 64)
// ---------------------------------------------------------------------------
__global__ __launch_bounds__(256) void fcg_prep(
    const float* __restrict__ fc_w, const float* __restrict__ gate_w,
    __hip_bfloat16* __restrict__ fcgT)
{
    int tid = blockIdx.x * 256 + threadIdx.x;  // 32768
    int np = tid >> 6, k = tid & 63;
    int o = (np >> 5) * 16 + (np & 15);
    const float* src = ((np >> 4) & 1) ? gate_w : fc_w;
    fcgT[tid] = __float2bfloat16(src[k * 256 + o]);
}

// ---------------------------------------------------------------------------
// Generic fp32 tiled GEMM (krow only)
// ---------------------------------------------------------------------------
#define GM_BM 64
#define GM_BN 64
#define GM_BK 16

__global__ __launch_bounds__(256) void gemm_nn(
    const float* __restrict__ A, const float* __restrict__ Bm, float* __restrict__ C,
    int M, int N, int K, int lda, int ldb, int ldc,
    long sA, long sB, long sC)
{
    const int z = blockIdx.z;
    A += (long)z * sA; Bm += (long)z * sB; C += (long)z * sC;
    const int m0 = blockIdx.y * GM_BM;
    const int n0 = blockIdx.x * GM_BN;
    const int tid = threadIdx.x;
    const int tx = tid & 15;
    const int ty = tid >> 4;

    __shared__ float As[GM_BK][GM_BM + 4];
    __shared__ float Bs[GM_BK][GM_BN + 4];

    float acc[4][4] = {};

    for (int k0 = 0; k0 < K; k0 += GM_BK) {
#pragma unroll
        for (int i = 0; i < 4; ++i) {
            int idx = tid + i * 256;
            int r = idx >> 4, c = idx & 15;
            As[c][r] = A[(long)(m0 + r) * lda + k0 + c];
        }
#pragma unroll
        for (int i = 0; i < 4; ++i) {
            int idx = tid + i * 256;
            int r = idx >> 6, c = idx & 63;
            Bs[r][c] = Bm[(long)(k0 + r) * ldb + n0 + c];
        }
        __syncthreads();
#pragma unroll
        for (int kk = 0; kk < GM_BK; ++kk) {
            float4 a4 = *(const float4*)&As[kk][ty * 4];
            float4 b4 = *(const float4*)&Bs[kk][tx * 4];
            float av[4] = {a4.x, a4.y, a4.z, a4.w};
            float bv[4] = {b4.x, b4.y, b4.z, b4.w};
#pragma unroll
            for (int i = 0; i < 4; ++i)
#pragma unroll
                for (int j = 0; j < 4; ++j)
                    acc[i][j] += av[i] * bv[j];
        }
        __syncthreads();
    }
#pragma unroll
    for (int i = 0; i < 4; ++i) {
        long m = m0 + ty * 4 + i;
#pragma unroll
        for (int j = 0; j < 4; ++j) {
            int n = n0 + tx * 4 + j;
            C[m * ldc + n] = acc[i][j];
        }
    }
}

// ---------------------------------------------------------------------------
// fp32 GEMM with N-major B: C(MxN) = A(MxK) @ BT(NxK)^T, batched z over BT/C.
// Used for p[b, n*256+i] = krow[b,:] . Wq_i[n][i][:]  (mask path, fp32-exact).
// ---------------------------------------------------------------------------
__global__ __launch_bounds__(256) void gemm_nt_f32(
    const float* __restrict__ A, int lda,
    const float* __restrict__ BT, int ldb,
    float* __restrict__ C, int ldc, int K, long sB, long sC)
{
    BT += (long)blockIdx.z * sB;
    C  += (long)blockIdx.z * sC;
    const int m0 = blockIdx.y * 64;
    const int n0 = blockIdx.x * 64;
    const int tid = threadIdx.x;
    const int tx = tid & 15;
    const int ty = tid >> 4;

    __shared__ float As[16][68];
    __shared__ float Bs[64][17];

    float acc[4][4] = {};

    for (int k0 = 0; k0 < K; k0 += 16) {
#pragma unroll
        for (int i = 0; i < 4; ++i) {
            int idx = tid + i * 256;
            int r = idx >> 4, c = idx & 15;
            As[c][r] = A[(long)(m0 + r) * lda + k0 + c];
        }
#pragma unroll
        for (int i = 0; i < 4; ++i) {
            int idx = tid + i * 256;
            int r = idx >> 4, c = idx & 15;
            Bs[r][c] = BT[(long)(n0 + r) * ldb + k0 + c];
        }
        __syncthreads();
#pragma unroll
        for (int kk = 0; kk < 16; ++kk) {
            float4 a4 = *(const float4*)&As[kk][ty * 4];
            float av[4] = {a4.x, a4.y, a4.z, a4.w};
            float bv[4];
#pragma unroll
            for (int j = 0; j < 4; ++j) bv[j] = Bs[tx * 4 + j][kk];
#pragma unroll
            for (int i = 0; i < 4; ++i)
#pragma unroll
                for (int j = 0; j < 4; ++j)
                    acc[i][j] += av[i] * bv[j];
        }
        __syncthreads();
    }
#pragma unroll
    for (int i = 0; i < 4; ++i) {
        long m = m0 + ty * 4 + i;
#pragma unroll
        for (int j = 0; j < 4; ++j) {
            int n = n0 + tx * 4 + j;
            C[m * ldc + n] = acc[i][j];
        }
    }
}

// ---------------------------------------------------------------------------
// Fused s1 / sigmoid / top-k mask: s1[b,n] = (hx3[b,n,:] . p[b,n,:]) / 8.
// One wave per b, 4 waves per block. Rank logic identical to verified version.
// ---------------------------------------------------------------------------
__global__ __launch_bounds__(256) void s1_mask_fused(
    const float* __restrict__ hx,   // (B,2048)
    const float* __restrict__ p,    // (B,2048)  p[b, n*256+i]
    float* __restrict__ a_buf, float* __restrict__ mask_buf)
{
    const int wave = threadIdx.x >> 6;
    const int lane = threadIdx.x & 63;
    const long b = (long)blockIdx.x * 4 + wave;
    const long base = b * 2048 + lane * 4;
    float s1v[8];
#pragma unroll
    for (int n = 0; n < 8; ++n) {
        float4 hv = *(const float4*)(hx + base + n * 256);
        float4 pv = *(const float4*)(p + base + n * 256);
        float s = hv.x * pv.x + hv.y * pv.y + hv.z * pv.z + hv.w * pv.w;
#pragma unroll
        for (int off = 32; off > 0; off >>= 1) s += __shfl_xor(s, off, 64);
        s1v[n] = s * 0.125f;
    }
    unsigned maskbits = 0;
#pragma unroll
    for (int n = 0; n < 8; ++n) {
        int rank = 0;
#pragma unroll
        for (int m = 0; m < 8; ++m) {
            if (m == n) continue;
            if (s1v[m] < s1v[n] || (s1v[m] == s1v[n] && m < n)) rank++;
        }
        if (rank >= 4) maskbits |= (1u << n);
    }
    if (lane < 8) {
        float sv = s1v[0];
#pragma unroll
        for (int n = 1; n < 8; ++n)
            if (lane == n) sv = s1v[n];
        a_buf[b * 8 + lane] = sigmoidf_(sv);
        mask_buf[b * 8 + lane] = ((maskbits >> lane) & 1u) ? 1.0f : 0.0f;
    }
}

// ---------------------------------------------------------------------------
// MFMA GEMM: C(bf16, MxN) = A(bf16, MxK, lda) @ BT(bf16, NxK, ldb)^T
// ---------------------------------------------------------------------------
__global__ __launch_bounds__(256) void gemm_mfma_obf16(
    const __hip_bfloat16* __restrict__ A, int lda,
    const __hip_bfloat16* __restrict__ BT, int ldb,
    __hip_bfloat16* __restrict__ C, int ldc, int K)
{
    const int m0 = blockIdx.y * 128;
    const int n0 = blockIdx.x * 64;
    const int tid = threadIdx.x;
    const int lane = tid & 63, wid = tid >> 6;
    const int wr = wid >> 1, wc = wid & 1;
    const int l15 = lane & 15, l4 = lane >> 4;

    __shared__ __align__(16) char lds_raw[16384 + 8192];
    char* Alds = lds_raw;
    char* Blds = lds_raw + 16384;

    f32x4 acc[4][2] = {};

    for (int k0 = 0; k0 < K; k0 += 64) {
#pragma unroll
        for (int ii = 0; ii < 4; ++ii) {
            int issue = ii * 4 + wid;
            int chunk = issue * 64 + lane;
            int r = chunk >> 3, cs = chunk & 7;
            int cl = cs ^ (r & 7);
            const __hip_bfloat16* g = A + (long)(m0 + r) * lda + k0 + cl * 8;
            GLDS16(g, Alds + issue * 1024);
        }
#pragma unroll
        for (int jj = 0; jj < 2; ++jj) {
            int issue = jj * 4 + wid;
            int chunk = issue * 64 + lane;
            int r = chunk >> 3, cs = chunk & 7;
            int cl = cs ^ (r & 7);
            const __hip_bfloat16* g = BT + (long)(n0 + r) * ldb + k0 + cl * 8;
            GLDS16(g, Blds + issue * 1024);
        }
        __syncthreads();
#pragma unroll
        for (int kk = 0; kk < 2; ++kk) {
            bf16x8 af[4], bfr[2];
#pragma unroll
            for (int im = 0; im < 4; ++im) {
                int r = wr * 64 + im * 16 + l15;
                int cl = (kk * 4 + l4) ^ (l15 & 7);
                af[im] = *(const bf16x8*)(Alds + r * 128 + cl * 16);
            }
#pragma unroll
            for (int jn = 0; jn < 2; ++jn) {
                int r = wc * 32 + jn * 16 + l15;
                int cl = (kk * 4 + l4) ^ (l15 & 7);
                bfr[jn] = *(const bf16x8*)(Blds + r * 128 + cl * 16);
            }
#pragma unroll
            for (int im = 0; im < 4; ++im)
#pragma unroll
                for (int jn = 0; jn < 2; ++jn)
                    acc[im][jn] = __builtin_amdgcn_mfma_f32_16x16x32_bf16(
                        af[im], bfr[jn], acc[im][jn], 0, 0, 0);
        }
        __syncthreads();
    }
#pragma unroll
    for (int im = 0; im < 4; ++im)
#pragma unroll
        for (int reg = 0; reg < 4; ++reg) {
            long m = m0 + wr * 64 + im * 16 + l4 * 4 + reg;
#pragma unroll
            for (int jn = 0; jn < 2; ++jn) {
                int n = n0 + wc * 32 + jn * 16 + l15;
                C[m * ldc + n] = __float2bfloat16(acc[im][jn][reg]);
            }
        }
}

// ---------------------------------------------------------------------------
// Fused q/k/v_m projections (bf16 out).
// ---------------------------------------------------------------------------
__global__ __launch_bounds__(256) void gemm_mfma_qkv(
    const __hip_bfloat16* __restrict__ hnewb,  // (B,2048)
    const __hip_bfloat16* __restrict__ WmT,    // (8,192,256)
    __hip_bfloat16* __restrict__ qout)         // q|k|v, each 2097152 bf16
{
    const int z = blockIdx.z;
    const int m0 = blockIdx.y * 128;
    const int n0 = blockIdx.x * 64;
    const int tid = threadIdx.x;
    const int lane = tid & 63, wid = tid >> 6;
    const int wr = wid >> 1, wc = wid & 1;
    const int l15 = lane & 15, l4 = lane >> 4;

    const __hip_bfloat16* A = hnewb + z * 256;
    const __hip_bfloat16* BT = WmT + (long)z * 192 * 256;

    __shared__ __align__(16) char lds_raw[16384 + 8192];
    char* Alds = lds_raw;
    char* Blds = lds_raw + 16384;

    f32x4 acc[4][2] = {};

    for (int k0 = 0; k0 < 256; k0 += 64) {
#pragma unroll
        for (int ii = 0; ii < 4; ++ii) {
            int issue = ii * 4 + wid;
            int chunk = issue * 64 + lane;
            int r = chunk >> 3, cs = chunk & 7;
            int cl = cs ^ (r & 7);
            const __hip_bfloat16* g = A + (long)(m0 + r) * 2048 + k0 + cl * 8;
            GLDS16(g, Alds + issue * 1024);
        }
#pragma unroll
        for (int jj = 0; jj < 2; ++jj) {
            int issue = jj * 4 + wid;
            int chunk = issue * 64 + lane;
            int r = chunk >> 3, cs = chunk & 7;
            int cl = cs ^ (r & 7);
            const __hip_bfloat16* g = BT + (long)(n0 + r) * 256 + k0 + cl * 8;
            GLDS16(g, Blds + issue * 1024);
        }
        __syncthreads();
#pragma unroll
        for (int kk = 0; kk < 2; ++kk) {
            bf16x8 af[4], bfr[2];
#pragma unroll
            for (int im = 0; im < 4; ++im) {
                int r = wr * 64 + im * 16 + l15;
                int cl = (kk * 4 + l4) ^ (l15 & 7);
                af[im] = *(const bf16x8*)(Alds + r * 128 + cl * 16);
            }
#pragma unroll
            for (int jn = 0; jn < 2; ++jn) {
                int r = wc * 32 + jn * 16 + l15;
                int cl = (kk * 4 + l4) ^ (l15 & 7);
                bfr[jn] = *(const bf16x8*)(Blds + r * 128 + cl * 16);
            }
#pragma unroll
            for (int im = 0; im < 4; ++im)
#pragma unroll
                for (int jn = 0; jn < 2; ++jn)
                    acc[im][jn] = __builtin_amdgcn_mfma_f32_16x16x32_bf16(
                        af[im], bfr[jn], acc[im][jn], 0, 0, 0);
        }
        __syncthreads();
    }
#pragma unroll
    for (int jn = 0; jn < 2; ++jn) {
        int j = n0 + wc * 32 + jn * 16 + l15;   // [0,192)
        int g = j >> 6, d = j & 63;
        __hip_bfloat16* outp = qout + (long)g * 2097152 + (long)z * 64 + d;
#pragma unroll
        for (int im = 0; im < 4; ++im)
#pragma unroll
            for (int reg = 0; reg < 4; ++reg) {
                long m = m0 + wr * 64 + im * 16 + l4 * 4 + reg;
                outp[m * 512] = __float2bfloat16(acc[im][jn][reg]);
            }
    }
}

// ---------------------------------------------------------------------------
// MFMA big GEMM + fused GRU epilogue. 512 thr / 8 waves; block tile
// 128m x (64ol x 3g = 192n); wave = 32m x (32ol x 3g); one barrier-pair per
// K-step covers 192 block-MFMAs (2x the old 96) -> halved barrier overhead.
// XCD-pinned kblk = bid&7.
// ---------------------------------------------------------------------------
__global__ __launch_bounds__(512) void gru_fused_mfma(
    const __hip_bfloat16* __restrict__ wfcb,   // (B,1024)
    const __hip_bfloat16* __restrict__ hxb,    // (B,2048)
    const float* __restrict__ a_buf,           // (B,8)
    const float* __restrict__ cb,              // (8,768)
    const __hip_bfloat16* __restrict__ Wihb,   // (8,768,1024)
    const __hip_bfloat16* __restrict__ Whhb,   // (8,768,256)
    const float* __restrict__ bhh,             // (8,768)
    __hip_bfloat16* __restrict__ hnewb)        // (B,2048)
{
    const int bid = blockIdx.x;
    const int kblk = bid & 7;
    const int r_ = bid >> 3;
    const int ol0 = (r_ & 3) * 64;     // 4 ol-blocks of 64
    const int m0 = (r_ >> 2) * 128;    // 32 m-blocks
    const int tid = threadIdx.x;
    const int lane = tid & 63, wid = tid >> 6;   // wid 0..7
    const int wr = wid >> 1;                     // 0..3 : 32-row group
    const int wc = wid & 1;                      // 0..1 : 32-ol group
    const int l15 = lane & 15, l4 = lane >> 4;

    __shared__ __align__(16) char lds_raw[16384 + 24576];
    char* Alds = lds_raw;
    char* Blds = lds_raw + 16384;

    f32x4 accx[2][3][2] = {};
    f32x4 acch[2][3][2] = {};

#define STAGE(Asrc, sA, Bsrc, sB, k0) do {                                     \
    for (int ii = wid; ii < 16; ii += 8) {                                     \
        int chunk = ii * 64 + lane;                                            \
        int r = chunk >> 3, cs = chunk & 7;                                    \
        int cl = cs ^ (r & 7);                                                 \
        const __hip_bfloat16* g = (Asrc) + (long)(m0 + r) * (sA) + (k0) + cl * 8; \
        GLDS16(g, Alds + ii * 1024);                                           \
    }                                                                          \
    for (int jj = wid; jj < 24; jj += 8) {                                     \
        int chunk = jj * 64 + lane;                                            \
        int r = chunk >> 3, cs = chunk & 7;                                    \
        int cl = cs ^ (r & 7);                                                 \
        int gg = r >> 6, oll = r & 63;                                         \
        const __hip_bfloat16* g = (Bsrc) + (long)(gg * 256 + ol0 + oll) * (sB) + (k0) + cl * 8; \
        GLDS16(g, Blds + jj * 1024);                                           \
    }                                                                          \
} while (0)

#define COMPUTE(acc) do {                                                      \
    _Pragma("unroll") for (int kk = 0; kk < 2; ++kk) {                         \
        int cl = (kk * 4 + l4) ^ (l15 & 7);                                    \
        bf16x8 af[2], bfr[3][2];                                               \
        _Pragma("unroll") for (int im = 0; im < 2; ++im) {                     \
            int r = wr * 32 + im * 16 + l15;                                   \
            af[im] = *(const bf16x8*)(Alds + r * 128 + cl * 16);               \
        }                                                                      \
        _Pragma("unroll") for (int g = 0; g < 3; ++g)                          \
            _Pragma("unroll") for (int jn = 0; jn < 2; ++jn) {                 \
                int r = g * 64 + wc * 32 + jn * 16 + l15;                      \
                bfr[g][jn] = *(const bf16x8*)(Blds + r * 128 + cl * 16);       \
            }                                                                  \
        _Pragma("unroll") for (int im = 0; im < 2; ++im)                       \
            _Pragma("unroll") for (int g = 0; g < 3; ++g)                      \
                _Pragma("unroll") for (int jn = 0; jn < 2; ++jn)               \
                    acc[im][g][jn] = __builtin_amdgcn_mfma_f32_16x16x32_bf16(  \
                        af[im], bfr[g][jn], acc[im][g][jn], 0, 0, 0);          \
    }                                                                          \
} while (0)

    const __hip_bfloat16* Wk = Wihb + (long)kblk * 768 * 1024;
    for (int k0 = 0; k0 < 1024; k0 += 64) {
        STAGE(wfcb, 1024, Wk, 1024, k0);
        __syncthreads();
        COMPUTE(accx);
        __syncthreads();
    }
    const __hip_bfloat16* Wh = Whhb + (long)kblk * 768 * 256;
    const __hip_bfloat16* hxk = hxb + kblk * 256;
    for (int k0 = 0; k0 < 256; k0 += 64) {
        STAGE(hxk, 2048, Wh, 256, k0);
        __syncthreads();
        COMPUTE(acch);
        __syncthreads();
    }
#undef STAGE
#undef COMPUTE

    const float* cbk = cb + kblk * 768;
    const float* bhk = bhh + kblk * 768;
#pragma unroll
    for (int jn = 0; jn < 2; ++jn) {
        const int ol = ol0 + wc * 32 + jn * 16 + l15;
        const float cb0 = cbk[ol], cb1 = cbk[256 + ol], cb2 = cbk[512 + ol];
        const float bh0 = bhk[ol], bh1 = bhk[256 + ol], bh2 = bhk[512 + ol];
#pragma unroll
        for (int im = 0; im < 2; ++im) {
#pragma unroll
            for (int reg = 0; reg < 4; ++reg) {
                long m = m0 + wr * 32 + im * 16 + l4 * 4 + reg;
                float av = a_buf[m * 8 + kblk];
                float gx0 = av * accx[im][0][jn][reg] + cb0;
                float gx1 = av * accx[im][1][jn][reg] + cb1;
                float gx2 = av * accx[im][2][jn][reg] + cb2;
                float gh0 = acch[im][0][jn][reg] + bh0;
                float gh1 = acch[im][1][jn][reg] + bh1;
                float gh2 = acch[im][2][jn][reg] + bh2;
                float rr = sigmoidf_(gx0 + gh0);
                float zz = sigmoidf_(gx1 + gh1);
                float nn = tanhf(gx2 + rr * gh2);
                long idx = m * 2048 + kblk * 256 + ol;
                float hxv = __bfloat162float(hxb[idx]);
                hnewb[idx] = __float2bfloat16((1.f - zz) * nn + zz * hxv);
            }
        }
    }
}

// ---------------------------------------------------------------------------
// Memory attention (bf16 in/out)
// ---------------------------------------------------------------------------
__global__ __launch_bounds__(256) void mattn_kernel(
    const __hip_bfloat16* __restrict__ qm, const __hip_bfloat16* __restrict__ km,
    const __hip_bfloat16* __restrict__ vm, __hip_bfloat16* __restrict__ omb)
{
    const int t = threadIdx.x;
    const int local = t & 31;
    const long b = (long)blockIdx.x * 8 + (t >> 5);
    const int h = local >> 3, qn = local & 7;
    const long base = b * 512 + h * 16;

    float qv[16];
#pragma unroll
    for (int i = 0; i < 2; ++i) {
        bf16x8 v = *(const bf16x8*)(qm + base + qn * 64 + i * 8);
#pragma unroll
        for (int j = 0; j < 8; ++j) qv[i * 8 + j] = (float)v[j];
    }
    float sc[8];
#pragma unroll
    for (int kn = 0; kn < 8; ++kn) {
        float s = 0.f;
#pragma unroll
        for (int i = 0; i < 2; ++i) {
            bf16x8 v = *(const bf16x8*)(km + base + kn * 64 + i * 8);
#pragma unroll
            for (int j = 0; j < 8; ++j) s += qv[i * 8 + j] * (float)v[j];
        }
        sc[kn] = s * 0.25f;
    }
    float mx = sc[0];
#pragma unroll
    for (int kn = 1; kn < 8; ++kn) mx = fmaxf(mx, sc[kn]);
    float ssum = 0.f;
#pragma unroll
    for (int kn = 0; kn < 8; ++kn) { sc[kn] = expf(sc[kn] - mx); ssum += sc[kn]; }
    float inv = 1.f / ssum;

    float acc[16] = {};
#pragma unroll
    for (int kn = 0; kn < 8; ++kn) {
        float w = sc[kn] * inv;
#pragma unroll
        for (int i = 0; i < 2; ++i) {
            bf16x8 v = *(const bf16x8*)(vm + base + kn * 64 + i * 8);
#pragma unroll
            for (int j = 0; j < 8; ++j) acc[i * 8 + j] += w * (float)v[j];
        }
    }
#pragma unroll
    for (int i = 0; i < 2; ++i) {
        bf16x8 o;
#pragma unroll
        for (int j = 0; j < 8; ++j) o[j] = (__bf16)acc[i * 8 + j];
        *(bf16x8*)(omb + base + qn * 64 + i * 8) = o;
    }
}

// ---------------------------------------------------------------------------
// att GEMM: (32768 x 64) om @ fcgT(512x64)^T with fused sig*tanh epilogue.
// ---------------------------------------------------------------------------
__global__ __launch_bounds__(256) void att_gemm(
    const __hip_bfloat16* __restrict__ omb,    // (32768,64)
    const __hip_bfloat16* __restrict__ fcgT,   // (512,64)
    const float* __restrict__ fc_b, const float* __restrict__ gate_b,
    __hip_bfloat16* __restrict__ attb)         // (32768,256) == (B,2048)
{
    const int m0 = blockIdx.y * 128;
    const int n0 = blockIdx.x * 64;
    const int tid = threadIdx.x;
    const int lane = tid & 63, wid = tid >> 6;
    const int wr = wid >> 1, wc = wid & 1;
    const int l15 = lane & 15, l4 = lane >> 4;

    __shared__ __align__(16) char lds_raw[16384 + 8192];
    char* Alds = lds_raw;
    char* Blds = lds_raw + 16384;

    f32x4 acc[4][2] = {};
#pragma unroll
    for (int ii = 0; ii < 4; ++ii) {
        int issue = ii * 4 + wid;
        int chunk = issue * 64 + lane;
        int r = chunk >> 3, cs = chunk & 7;
        int cl = cs ^ (r & 7);
        const __hip_bfloat16* g = omb + (long)(m0 + r) * 64 + cl * 8;
        GLDS16(g, Alds + issue * 1024);
    }
#pragma unroll
    for (int jj = 0; jj < 2; ++jj) {
        int issue = jj * 4 + wid;
        int chunk = issue * 64 + lane;
        int r = chunk >> 3, cs = chunk & 7;
        int cl = cs ^ (r & 7);
        const __hip_bfloat16* g = fcgT + (long)(n0 + r) * 64 + cl * 8;
        GLDS16(g, Blds + issue * 1024);
    }
    __syncthreads();
#pragma unroll
    for (int kk = 0; kk < 2; ++kk) {
        bf16x8 af[4], bfr[2];
#pragma unroll
        for (int im = 0; im < 4; ++im) {
            int r = wr * 64 + im * 16 + l15;
            int cl = (kk * 4 + l4) ^ (l15 & 7);
            af[im] = *(const bf16x8*)(Alds + r * 128 + cl * 16);
        }
#pragma unroll
        for (int jn = 0; jn < 2; ++jn) {
            int r = wc * 32 + jn * 16 + l15;
            int cl = (kk * 4 + l4) ^ (l15 & 7);
            bfr[jn] = *(const bf16x8*)(Blds + r * 128 + cl * 16);
        }
#pragma unroll
        for (int im = 0; im < 4; ++im)
#pragma unroll
            for (int jn = 0; jn < 2; ++jn)
                acc[im][jn] = __builtin_amdgcn_mfma_f32_16x16x32_bf16(
                    af[im], bfr[jn], acc[im][jn], 0, 0, 0);
    }
    const int o = ((n0 + wc * 32) >> 1) + l15;
    const float fb = fc_b[o], gb = gate_b[o];
#pragma unroll
    for (int im = 0; im < 4; ++im)
#pragma unroll
        for (int reg = 0; reg < 4; ++reg) {
            long m = m0 + wr * 64 + im * 16 + l4 * 4 + reg;
            float att = sigmoidf_(acc[im][1][reg] + gb) * tanhf(acc[im][0][reg] + fb);
            attb[m * 256 + o] = __float2bfloat16(att);
        }
}

// ---------------------------------------------------------------------------
// Final elementwise: h2 = hnewb + attb; masked select; mask_w write.
// ---------------------------------------------------------------------------
__global__ __launch_bounds__(256) void final_elem(
    const __hip_bfloat16* __restrict__ hnewb, const __hip_bfloat16* __restrict__ attb,
    const float* __restrict__ maskb,
    const float* __restrict__ hx, const float* __restrict__ cx,
    float* __restrict__ hx_out, float* __restrict__ cx_out, float* __restrict__ mask_w)
{
    long i4 = (long)blockIdx.x * 256 + threadIdx.x;   // 2,097,152 quads
    long e = i4 * 4;
    int n = (int)((e >> 8) & 7);
    long b = e >> 11;
    float mv = maskb[b * 8 + n];
    ushort4 hn = ((const ushort4*)hnewb)[i4];
    ushort4 at = ((const ushort4*)attb)[i4];
    float4 hxv = ((const float4*)hx)[i4];
    float4 cxv = ((const float4*)cx)[i4];
    float4 h2;
    h2.x = b2f_(hn.x) + b2f_(at.x);
    h2.y = b2f_(hn.y) + b2f_(at.y);
    h2.z = b2f_(hn.z) + b2f_(at.z);
    h2.w = b2f_(hn.w) + b2f_(at.w);
    bool k = (mv != 0.f);
    float4 ho = k ? h2 : hxv;
    float4 co = k ? h2 : cxv;
    ((float4*)hx_out)[i4] = ho;
    ((float4*)cx_out)[i4] = co;
    ((float4*)mask_w)[i4] = make_float4(mv, mv, mv, mv);
}

// ---------------------------------------------------------------------------
extern "C" void kernel_launch(void* const* d_in, const int* in_sizes, int n_in,
                              void* d_out, int out_size, void* d_ws, size_t ws_size,
                              hipStream_t stream)
{
    const float* inp     = (const float*)d_in[0];
    const float* hx      = (const float*)d_in[1];
    const float* cx      = (const float*)d_in[2];
    const float* Wq_i    = (const float*)d_in[4];
    const float* Wk_i    = (const float*)d_in[5];
    const float* Wv_i    = (const float*)d_in[6];
    const float* fc_i_w  = (const float*)d_in[7];
    const float* fc_i_b  = (const float*)d_in[8];
    const float* Wq_m    = (const float*)d_in[9];
    const float* Wk_m    = (const float*)d_in[10];
    const float* Wv_m    = (const float*)d_in[11];
    const float* fc_m_w  = (const float*)d_in[12];
    const float* fc_m_b  = (const float*)d_in[13];
    const float* gate_m_w= (const float*)d_in[14];
    const float* gate_m_b= (const float*)d_in[15];
    const float* Wih     = (const float*)d_in[16];
    const float* Whh     = (const float*)d_in[17];
    const float* bih     = (const float*)d_in[18];
    const float* bhh     = (const float*)d_in[19];

    float* out = (float*)d_out;
    const long BH = (long)B_SZ * NHID_;   // 8388608
    float* hx_out = out;
    float* cx_out = out + BH;
    float* mask_w = out + 2 * BH;
    __hip_bfloat16* hxb = (__hip_bfloat16*)out;   // bf16 hx in hx_out region (dead after gru)
    __hip_bfloat16* qkvb = (__hip_bfloat16*)out;  // q|k|v bf16, written post-gru
    float* pbuf = cx_out;                         // (B,2048) f32 p, dead before final_elem

    // Workspace layout (float offsets; all sizes exact):
    float* w = (float*)d_ws;
    float* a_buf = w;                                        // [0, 32768)
    float* maskb = w + 32768;                                // [32768, 65536)
    float* cbuf  = w + 65536;                                // [65536, 71680)
    __hip_bfloat16* fcgT = (__hip_bfloat16*)(w + 73728);     // 32768 bf16   -> [73728, 90112)
    __hip_bfloat16* WmT  = (__hip_bfloat16*)(w + 90112);     // 393216 bf16  -> [90112, 286720)
    __hip_bfloat16* Wihb = (__hip_bfloat16*)(w + 286720);    // 6291456 bf16 -> [286720, 3432448)
    __hip_bfloat16* Whhb = (__hip_bfloat16*)(w + 3432448);   // 1572864 bf16 -> [3432448, 4218880)
    __hip_bfloat16* wfcb = (__hip_bfloat16*)(w + 4218880);   // 4194304 bf16 -> [4218880, 6316032)
    __hip_bfloat16* hnewb= (__hip_bfloat16*)(w + 6316032);   // 8388608 bf16 -> [6316032, 10510336)
    // pre-gru overlays inside hnewb's region (dead before gru writes hnewb):
    float* krow = w + 8413184;                               // [8413184, 8675328)
    __hip_bfloat16* inpb = (__hip_bfloat16*)(w + 8675328);   // 2097152 bf16 -> [8675328, 9723904)
    __hip_bfloat16* WvB  = (__hip_bfloat16*)(w + 9723904);   // 524288 bf16  -> [9723904, 9986048)
    __hip_bfloat16* fcT  = (__hip_bfloat16*)(w + 9986048);   // 1048576 bf16 -> [9986048, 10510336)
    __hip_bfloat16* WvFT = (__hip_bfloat16*)(w + 10510336);  // 524288 bf16  -> [10510336, 10772480)
    // post-gru overlays (Wihb/Whhb/wfcb dead):
    __hip_bfloat16* omb  = (__hip_bfloat16*)(w + 286720);    // 2097152 bf16 -> [286720, 1335296)
    __hip_bfloat16* attb = (__hip_bfloat16*)(w + 1335296);   // 8388608 bf16 -> [1335296, 5529600)

    // ---- Phase A: conversions / prep ----
    wih_prep<<<dim3(6144), dim3(256), 0, stream>>>(Wih, fc_i_b, bih, Wihb, cbuf);
    f2b_kernel<<<dim3(2048), dim3(256), 0, stream>>>(hx, hxb, 2097152);
    f2b_kernel<<<dim3(1024), dim3(256), 0, stream>>>(inp, inpb, 524288);
    f2b_kernel<<<dim3(1024), dim3(256), 0, stream>>>(Whh, Whhb, 393216);
    f2b_kernel<<<dim3(512), dim3(256), 0, stream>>>(Wv_i + 512 * 1024, WvB, 131072);
    tconv_kernel<<<dim3(32, 32, 1), dim3(256), 0, stream>>>(fc_i_w, 1024, 0, fcT, 1024, 0);
    tconv_kernel<<<dim3(2, 8, 8), dim3(256), 0, stream>>>(Wq_m, 64, 16384, WmT, 256, 49152);
    tconv_kernel<<<dim3(2, 8, 8), dim3(256), 0, stream>>>(Wk_m, 64, 16384, WmT + 64 * 256, 256, 49152);
    tconv_kernel<<<dim3(2, 8, 8), dim3(256), 0, stream>>>(Wv_m, 64, 16384, WmT + 128 * 256, 256, 49152);
    fcg_prep<<<dim3(128), dim3(256), 0, stream>>>(fc_m_w, gate_m_w, fcgT);
    // ---- Phase B: mask path (fp32, reordered contraction) ----
    // krow = inp @ Wk_i[1]  (4096x64, K=512)
    gemm_nn<<<dim3(1, 64, 1), dim3(256), 0, stream>>>(
        inp, Wk_i + 512 * 64, krow, 4096, 64, 512, 512, 64, 64, 0, 0, 0);
    // p[b, n*256+i] = krow[b,:] . Wq_i[n][i][:]   (M=4096,N=256,K=64, z=8)
    gemm_nt_f32<<<dim3(4, 64, 8), dim3(256), 0, stream>>>(
        krow, 64, Wq_i, 64, pbuf, 2048, 64, 16384, 256);
    // s1 = (hx3 . p)/8 -> sigmoid + top-k mask
    s1_mask_fused<<<dim3(1024), dim3(256), 0, stream>>>(hx, pbuf, a_buf, maskb);
    // WvFT(1024x512) = fcT(1024x1024) @ WvB(512x1024)^T
    gemm_mfma_obf16<<<dim3(8, 8, 1), dim3(256), 0, stream>>>(
        fcT, 1024, WvB, 1024, WvFT, 512, 1024);
    // wfcb(4096x1024) = inpb(4096x512) @ WvFT^T
    gemm_mfma_obf16<<<dim3(16, 32, 1), dim3(256), 0, stream>>>(
        inpb, 512, WvFT, 512, wfcb, 1024, 512);
    // ---- Phase C: fused MFMA GEMM + GRU -> hnewb (512-thr, 192-wide tile) ----
    gru_fused_mfma<<<dim3(1024), dim3(512), 0, stream>>>(
        wfcb, hxb, a_buf, cbuf, Wihb, Whhb, bhh, hnewb);
    // ---- Phase D: q/k/v_m projections (bf16, into hx_out region) ----
    gemm_mfma_qkv<<<dim3(3, 32, 8), dim3(256), 0, stream>>>(hnewb, WmT, qkvb);
    // ---- Phase E: memory attention + att GEMM + final ----
    mattn_kernel<<<dim3(512), dim3(256), 0, stream>>>(
        qkvb, qkvb + 2097152, qkvb + 4194304, omb);
    att_gemm<<<dim3(8, 256, 1), dim3(256), 0, stream>>>(omb, fcgT, fc_m_b, gate_m_b, attb);
    final_elem<<<dim3(8192), dim3(256), 0, stream>>>(
        hnewb, attb, maskb, hx, cx, hx_out, cx_out, mask_w);
}